// Round 1
// 103.045 us; speedup vs baseline: 1.3412x; 1.3412x over previous
//
#include <hip/hip_runtime.h>
#include <stdint.h>

// HamiltonianFlow: x [256, 8, 32, 2] (q,p); H = 0.5*sum(p^2) + MLP(q).
// dq/dt = p, dp/dt = -W u(z), z = W^T q + b1, u = (1-tanh^2(z)).*W2.
// z-space iteration with M = W^T W (R15-R23 verified).
//
// R25 = R24 + FOUR-STEP EXCHANGE: the 16x16x32 A-tile has 16 rows; R24 used
// only 4 distinct (4x redundant). Now rows 4q+r hold step-q stage-(r+1)
// u-vectors (q=quad, 4 RK4 steps per exchange) -> ONE barrier + ONE
// 16-MFMA block per FOUR steps (25 exchanges total). Quad q:
//   - predicts state (z_q, P_q) via prev-exchange butterfly sums SA,SB
//     (B_j ~ SB/4 average proxy; err ~1e-5 in stage-z, ~100x below f16
//     u-rounding, same budget argument as R23's lag),
//   - evaluates its step's 4 stage u's (lagged Y1^,Y2^ = OWN prev-exchange
//     C[0],C[1], lag-4 instead of lag-1: dz ~ 1e-6, benign),
//   - writes rows 4q..4q+3; barrier; MFMA -> C[0..3] = step-q Y1..Y4
//     (C-row = 4*quad+reg matches A-row ownership for free).
// Exact 4-step advance is linear in per-step combos A_j=Y1+Y2+Y3,
// B_j=Y1+2Y2+2Y3+Y4:  P+= -dt6*SB;  z += 4dt*P - dt*dt6*(SWB + SA)
// with SB=sum B_j, SWB=sum (3-j)B_j, SA=sum A_j -- three shfl_xor(16,32)
// butterflies (12 shfls), no cross-quad Y gather/ordering needed.
// S-sums: per-lane full sp,sq for its step; cn starts 99-quad, -=4.
//
// ubuf: 16 rows x US x 2 buffers = 17408 B, UNION'd with setup-only mscr
// (20480 B) to fit LDS (wldsT 135168 + 20480 = 155648 <= 163840); one
// added barrier between M-build and prologue ubuf writes.
// XOR swizzle on ubuf cols (elem c ^= ((row>>2)&3)<<3, 8-elem granular):
// 16 distinct 544B-strided rows would 4-way-conflict ds_read_b128 (rows
// s,s+4,s+8,s+12 alias: 4*544 % 128 == 0); swizzle spreads the four 16B
// slots. Prologue/epilogue rows 0-3 have swizzle 0 -> untouched.
// IEEE divide 2/(e+1) -> __builtin_amdgcn_rcpf (u rel err 1e-7 << f16).
// Double-buffer race argument (R24) unchanged: one barrier per exchange.
// FULL unroll on every reg-array access (R4: dynamic index => scratch).
// Numerics: f16 storage (W, M, u, S), fp32 MFMA accum + fp32 z1/P state.

typedef _Float16 v8h __attribute__((ext_vector_type(8)));
typedef float v4f __attribute__((ext_vector_type(4)));

#define NSTEPS 100
#define NEX 25    // 4 RK4 steps per exchange
#define WS 264    // wldsT row stride (f16): row = one W-COLUMN, 16B-aligned
#define US 272    // ubuf row stride, f16 (544 B == 32 mod 128)

// D(+=C) in VGPRs, A (packed-vector frag) in VGPRs, B (M-frag) from AGPRs.
#define MFMA_AV(C, A, B) \
    asm("v_mfma_f32_16x16x32_f16 %0, %1, %2, %0" : "+v"(C) : "v"(A), "a"(B))

__device__ __forceinline__ float ueval(float z_, float w2r_) {
    float e_ = __expf(2.f * z_);
    float r_ = __builtin_amdgcn_rcpf(e_ + 1.f);   // vs IEEE div: ~1e-7 rel
    float hh = 1.f - 2.f * r_;
    return (1.f - hh * hh) * w2r_;
}

__global__ __launch_bounds__(512, 2)
void ham_kernel(const float* __restrict__ x0, const float* __restrict__ W1,
                const float* __restrict__ b1, const float* __restrict__ W2,
                float* __restrict__ out)
{
    __shared__ __align__(16)  _Float16 wldsT[256 * WS];  // 135168 B: W^T (f16)
    __shared__ __align__(128) char     upool[20480];     // mscr UNION ubuf
    float*    mscr = (float*)upool;                      // setup only
    _Float16* ubuf = (_Float16*)upool;                   // 2 x 16 rows x US

    const int t = threadIdx.x;
    const int w = t >> 6;          // wave 0..7: owns tiles {2w, 2w+1}
    const int l = t & 63;
    const int quad = l >> 4;       // step-within-exchange owned by this lane
    const int s = l & 15;          // owned column / A-row
    const int c0 = 32 * w + s;          // comp, tile 2w
    const int c1 = 32 * w + 16 + s;     // comp, tile 2w+1
    const int blk = blockIdx.x;
    const int sel = (s & 3) * US;  // prologue/epilogue A-row select (rows 0-3)

    // ---- stage W^T -> LDS f16: wldsT[c][r] = W[r][c] ----
    {
        const int c = t & 255;
        const int rbase = (t >> 8) * 128;
        #pragma unroll 1
        for (int r0 = 0; r0 < 128; r0 += 8) {
            v8h h;
            #pragma unroll
            for (int j = 0; j < 8; ++j)
                h[j] = (_Float16)W1[(rbase + r0 + j) * 256 + c];
            *(v8h*)(wldsT + c * WS + rbase + r0) = h;   // b128, one-time
        }
    }
    __syncthreads();

    // ---- wF: own-column W^T frags (B-op), contiguous b128 from wldsT ----
    v8h wF0[8], wF1[8];
    #pragma unroll
    for (int kk = 0; kk < 8; ++kk) {
        wF0[kk] = *(const v8h*)(wldsT + c0 * WS + 32 * kk + 8 * quad);
        wF1[kk] = *(const v8h*)(wldsT + c1 * WS + 32 * kk + 8 * quad);
    }

    // ---- build M = W^T W column-block frags wM0/wM1 (B-op: M[k][c]) ----
    v8h wM0[8], wM1[8];
    float* scr0 = mscr + w * 640;
    float* scr1 = scr0 + 320;
    #pragma unroll
    for (int kb = 0; kb < 16; ++kb) {
        v8h aM[8];   // A[m=s][k=8quad+j] = wldsT[(16kb+s)*WS + 32kk+8quad+j]
        #pragma unroll
        for (int kk = 0; kk < 8; ++kk)
            aM[kk] = *(const v8h*)(wldsT + (16 * kb + s) * WS
                                          + 32 * kk + 8 * quad);
        v4f D0 = {0.f,0.f,0.f,0.f}, D1 = {0.f,0.f,0.f,0.f};
        #pragma unroll
        for (int kk = 0; kk < 8; ++kk) {
            D0 = __builtin_amdgcn_mfma_f32_16x16x32_f16(aM[kk], wF0[kk], D0, 0, 0, 0);
            D1 = __builtin_amdgcn_mfma_f32_16x16x32_f16(aM[kk], wF1[kk], D1, 0, 0, 0);
        }
        *(v4f*)(scr0 + s * 20 + 4 * quad) = D0;
        *(v4f*)(scr1 + s * 20 + 4 * quad) = D1;
        asm volatile("s_waitcnt lgkmcnt(0)" ::: "memory");  // in-wave x-lane
        if ((quad >> 1) == (kb & 1)) {
            #pragma unroll
            for (int j = 0; j < 8; ++j) {
                wM0[kb >> 1][j] = (_Float16)scr0[s * 20 + 8 * (quad & 1) + j];
                wM1[kb >> 1][j] = (_Float16)scr1[s * 20 + 8 * (quad & 1) + j];
            }
        }
        asm volatile("s_waitcnt lgkmcnt(0)" ::: "memory");
    }
    __syncthreads();   // NEW: mscr reads (all waves) done before ubuf reuse

    const float b1r0 = b1[c0], b1r1 = b1[c1];
    const float w2r0 = W2[c0], w2r1 = W2[c1];
    float2 qp0 = ((const float2*)(x0 + (size_t)blk * 512))[c0];
    float2 qp1 = ((const float2*)(x0 + (size_t)blk * 512))[c1];
    const float q0o0 = qp0.x, p0o0 = qp0.y;
    const float q0o1 = qp1.x, p0o1 = qp1.y;

    // ---- prologue: buf0 rows {q0, p0, 0, 0} -> z1 (C[0]), P (C[1]) ----
    if (quad == 0) {
        ubuf[c0] = (_Float16)q0o0;  ubuf[c1] = (_Float16)q0o1;
        ubuf[US + c0] = (_Float16)p0o0;  ubuf[US + c1] = (_Float16)p0o1;
        ubuf[2 * US + c0] = (_Float16)0.f;  ubuf[2 * US + c1] = (_Float16)0.f;
        ubuf[3 * US + c0] = (_Float16)0.f;  ubuf[3 * US + c1] = (_Float16)0.f;
    }
    __syncthreads();
    float z10, P0, z11, P1;
    {
        const _Float16* ab = ubuf + sel + 8 * quad;
        v4f C0a = {0.f,0.f,0.f,0.f}, C0b = {0.f,0.f,0.f,0.f};
        v4f C1a = {0.f,0.f,0.f,0.f}, C1b = {0.f,0.f,0.f,0.f};
        #pragma unroll
        for (int kk = 0; kk < 8; kk += 2) {
            v8h a0 = *(const v8h*)(ab + 32 * kk);
            v8h a1 = *(const v8h*)(ab + 32 * (kk + 1));
            C0a = __builtin_amdgcn_mfma_f32_16x16x32_f16(a0, wF0[kk], C0a, 0, 0, 0);
            C1a = __builtin_amdgcn_mfma_f32_16x16x32_f16(a0, wF1[kk], C1a, 0, 0, 0);
            C0b = __builtin_amdgcn_mfma_f32_16x16x32_f16(a1, wF0[kk + 1], C0b, 0, 0, 0);
            C1b = __builtin_amdgcn_mfma_f32_16x16x32_f16(a1, wF1[kk + 1], C1b, 0, 0, 0);
        }
        v4f C0s = C0a + C0b, C1s = C1a + C1b;
        z10 = C0s[0] + b1r0;  P0 = C0s[1];
        z11 = C1s[0] + b1r1;  P1 = C1s[1];
    }
    __syncthreads();   // prologue reads done before iter-0 overwrites buf0

    const float dt = 0.01f, hdt = 0.005f, dt6 = 0.01f / 6.f;
    const float dtdt6 = dt * dt6, hdt2 = hdt * hdt, dthdt = dt * hdt;
    const float fourdt = 4.f * dt;
    // per-quad (step j = quad) prediction coefs:
    //   P_j ~ P - (j/4)*dt6*SBp ; z_j ~ z + j*dt*P - (j(j-1)/2)/4*dtdt6*SBp
    //                                    - (j/4)*dtdt6*SAp
    const float qf  = (float)quad;
    const float cP  = qf * 0.25f * dt6;
    const float cz1 = qf * dt;
    const float cz2 = (qf * (qf - 1.f) * 0.5f) * 0.25f * dtdt6;
    const float cz3 = qf * 0.25f * dtdt6;
    const float wB  = 3.f - qf;          // SWB weight (3-j)

    // ubuf addressing: write rows 4q+i at swizzled col c ^ (q<<3);
    // read row s at k-chunk 8*(quad ^ ((s>>2)&3))  [XOR involution]
    const int c0w = c0 ^ (quad << 3);
    const int c1w = c1 ^ (quad << 3);
    _Float16* wbase0 = ubuf + 4 * quad * US + c0w;
    _Float16* wbase1 = ubuf + 4 * quad * US + c1w;
    const int sx = (s >> 2) & 3;
    const _Float16* rb = ubuf + s * US + 8 * (quad ^ sx);

    // prev-exchange lag state (exchange 0: zeros -> same benign transient
    // class as R23 step-0, err ~1e-5 stage-z, one-time)
    float SAp0 = 0.f, SBp0 = 0.f, SAp1 = 0.f, SBp1 = 0.f;
    float Y1L0 = 0.f, Y2L0 = 0.f, Y1L1 = 0.f, Y2L1 = 0.f;
    float S1p0 = 0.f, S23p0 = 0.f, S1p1 = 0.f, S23p1 = 0.f;
    float cn = 99.f - qf;

    #pragma unroll 1
    for (int e = 0; e < NEX; ++e) {
        const int bo = (e & 1) * (16 * US);   // double-buffer offset

        // ---- predicted state for own step; 4 stage z's; 8 u evals ----
        float Pp0 = P0 - cP * SBp0;
        float Pp1 = P1 - cP * SBp1;
        float zp0 = z10 + cz1 * P0 - cz2 * SBp0 - cz3 * SAp0;
        float zp1 = z11 + cz1 * P1 - cz2 * SBp1 - cz3 * SAp1;
        float zb0 = zp0 + hdt * Pp0,              zb1 = zp1 + hdt * Pp1;
        float zc0 = zb0 - hdt2 * Y1L0,            zc1 = zb1 - hdt2 * Y1L1;
        float zd0 = zp0 + dt * Pp0 - dthdt * Y2L0;
        float zd1 = zp1 + dt * Pp1 - dthdt * Y2L1;

        float ua0 = ueval(zp0, w2r0), ua1 = ueval(zp1, w2r1);
        float ub0 = ueval(zb0, w2r0), ub1 = ueval(zb1, w2r1);
        float uc0 = ueval(zc0, w2r0), uc1 = ueval(zc1, w2r1);
        float ud0 = ueval(zd0, w2r0), ud1 = ueval(zd1, w2r1);

        _Float16* wp0 = wbase0 + bo;
        _Float16* wp1 = wbase1 + bo;
        wp0[0]      = (_Float16)ua0;  wp1[0]      = (_Float16)ua1;
        wp0[US]     = (_Float16)ub0;  wp1[US]     = (_Float16)ub1;
        wp0[2 * US] = (_Float16)uc0;  wp1[2 * US] = (_Float16)uc1;
        wp0[3 * US] = (_Float16)ud0;  wp1[3 * US] = (_Float16)ud1;
        __syncthreads();   // the ONLY barrier per exchange (4 steps)

        // ---- ONE MFMA block: step-q Y1..Y4 for both comps, in-lane ----
        float Y10, Y20, Y30, Y40, Y11, Y21, Y31, Y41;
        {
            const _Float16* ab = rb + bo;
            v4f C0a = {0.f,0.f,0.f,0.f}, C0b = {0.f,0.f,0.f,0.f};
            v4f C1a = {0.f,0.f,0.f,0.f}, C1b = {0.f,0.f,0.f,0.f};
            #pragma unroll
            for (int kk = 0; kk < 8; kk += 2) {
                v8h a0 = *(const v8h*)(ab + 32 * kk);
                v8h a1 = *(const v8h*)(ab + 32 * (kk + 1));
                MFMA_AV(C0a, a0, wM0[kk]);
                MFMA_AV(C1a, a0, wM1[kk]);
                MFMA_AV(C0b, a1, wM0[kk + 1]);
                MFMA_AV(C1b, a1, wM1[kk + 1]);
            }
            v4f C0s = C0a + C0b, C1s = C1a + C1b;
            Y10 = C0s[0]; Y20 = C0s[1]; Y30 = C0s[2]; Y40 = C0s[3];
            Y11 = C1s[0]; Y21 = C1s[1]; Y31 = C1s[2]; Y41 = C1s[3];
        }
        // no second barrier: next exchange writes the OTHER buffer (R24).

        // ---- exact 4-step advance via quad-weighted butterfly sums ----
        float tA0 = Y20 + Y30,         tA1 = Y21 + Y31;
        float A0  = Y10 + tA0,         A1  = Y11 + tA1;      // Y1+Y2+Y3
        float B0  = A0 + tA0 + Y40,    B1  = A1 + tA1 + Y41; // Y1+2Y2+2Y3+Y4
        float WB0 = wB * B0,           WB1 = wB * B1;
        A0  += __shfl_xor(A0, 16);   A0  += __shfl_xor(A0, 32);   // SA
        B0  += __shfl_xor(B0, 16);   B0  += __shfl_xor(B0, 32);   // SB
        WB0 += __shfl_xor(WB0, 16);  WB0 += __shfl_xor(WB0, 32);  // SWB
        A1  += __shfl_xor(A1, 16);   A1  += __shfl_xor(A1, 32);
        B1  += __shfl_xor(B1, 16);   B1  += __shfl_xor(B1, 32);
        WB1 += __shfl_xor(WB1, 16);  WB1 += __shfl_xor(WB1, 32);

        z10 += fourdt * P0 - dtdt6 * (WB0 + A0);   // z4 = z0+4dt P0
        P0  -= dt6 * B0;                           //      -dt*dt6*SWB-dtdt6*SA
        z11 += fourdt * P1 - dtdt6 * (WB1 + A1);
        P1  -= dt6 * B1;

        SAp0 = A0;  SBp0 = B0;  SAp1 = A1;  SBp1 = B1;   // lag sums
        Y1L0 = Y10; Y2L0 = Y20; Y1L1 = Y11; Y2L1 = Y21;  // own-step lag Ys

        // ---- per-lane S partials: full sp,sq for own step ----
        float tv0 = ub0 + uc0,                  tv1 = ub1 + uc1;
        float sp0 = ua0 + 2.f * tv0 + ud0,      sp1 = ua1 + 2.f * tv1 + ud1;
        float sq0 = ua0 + tv0,                  sq1 = ua1 + tv1;
        S1p0 += sp0;  S23p0 += cn * sp0 + sq0;
        S1p1 += sp1;  S23p1 += cn * sp1 + sq1;
        cn -= 4.f;
    }

    // ---- epilogue: reduce S over the 4 quads; buf0 rows {S1, S23, 0, 0} ----
    S1p0  += __shfl_xor(S1p0, 16, 64);   S1p0  += __shfl_xor(S1p0, 32, 64);
    S23p0 += __shfl_xor(S23p0, 16, 64);  S23p0 += __shfl_xor(S23p0, 32, 64);
    S1p1  += __shfl_xor(S1p1, 16, 64);   S1p1  += __shfl_xor(S1p1, 32, 64);
    S23p1 += __shfl_xor(S23p1, 16, 64);  S23p1 += __shfl_xor(S23p1, 32, 64);
    __syncthreads();   // last exchange's reads (buf0, e=24) done
    if (quad == 0) {
        ubuf[c0] = (_Float16)S1p0;       ubuf[c1] = (_Float16)S1p1;
        ubuf[US + c0] = (_Float16)S23p0; ubuf[US + c1] = (_Float16)S23p1;
        ubuf[2 * US + c0] = (_Float16)0.f;  ubuf[2 * US + c1] = (_Float16)0.f;
        ubuf[3 * US + c0] = (_Float16)0.f;  ubuf[3 * US + c1] = (_Float16)0.f;
    }
    __syncthreads();
    // wBt[kk][j] = W[c][32kk+8quad+j] = wldsT[(32kk+8quad+j)*WS + c]
    v8h wBt0[8], wBt1[8];
    #pragma unroll
    for (int kk = 0; kk < 8; ++kk)
        #pragma unroll
        for (int j = 0; j < 8; ++j) {
            wBt0[kk][j] = wldsT[(32 * kk + 8 * quad + j) * WS + c0];
            wBt1[kk][j] = wldsT[(32 * kk + 8 * quad + j) * WS + c1];
        }
    float D10, D20, D11, D21;
    {
        const _Float16* ab = ubuf + sel + 8 * quad;
        v4f C0a = {0.f,0.f,0.f,0.f}, C0b = {0.f,0.f,0.f,0.f};
        v4f C1a = {0.f,0.f,0.f,0.f}, C1b = {0.f,0.f,0.f,0.f};
        #pragma unroll
        for (int kk = 0; kk < 8; kk += 2) {
            v8h a0 = *(const v8h*)(ab + 32 * kk);
            v8h a1 = *(const v8h*)(ab + 32 * (kk + 1));
            C0a = __builtin_amdgcn_mfma_f32_16x16x32_f16(a0, wBt0[kk], C0a, 0, 0, 0);
            C1a = __builtin_amdgcn_mfma_f32_16x16x32_f16(a0, wBt1[kk], C1a, 0, 0, 0);
            C0b = __builtin_amdgcn_mfma_f32_16x16x32_f16(a1, wBt0[kk + 1], C0b, 0, 0, 0);
            C1b = __builtin_amdgcn_mfma_f32_16x16x32_f16(a1, wBt1[kk + 1], C1b, 0, 0, 0);
        }
        v4f C0s = C0a + C0b, C1s = C1a + C1b;
        D10 = C0s[0];  D20 = C0s[1];
        D11 = C1s[0];  D21 = C1s[1];
    }
    const float dt6e = 0.01f / 6.f, dtdt6e = 0.01f * dt6e;
    float pT0 = p0o0 - dt6e * D10;
    float qT0 = q0o0 + 0.01f * (float)NSTEPS * p0o0 - dtdt6e * D20;
    float pT1 = p0o1 - dt6e * D11;
    float qT1 = q0o1 + 0.01f * (float)NSTEPS * p0o1 - dtdt6e * D21;

    if (quad == 0) {
        ((float2*)(out + (size_t)blk * 512))[c0] = make_float2(qT0, pT0);
        ((float2*)(out + (size_t)blk * 512))[c1] = make_float2(qT1, pT1);
    }
}

extern "C" void kernel_launch(void* const* d_in, const int* in_sizes, int n_in,
                              void* d_out, int out_size, void* d_ws, size_t ws_size,
                              hipStream_t stream) {
    const float* x0 = (const float*)d_in[0];
    const float* W1 = (const float*)d_in[1];
    const float* b1 = (const float*)d_in[2];
    const float* W2 = (const float*)d_in[3];
    // d_in[4] = b2: constant offset, no effect on the gradient/dynamics.
    float* out = (float*)d_out;
    hipLaunchKernelGGL(ham_kernel, dim3(256), dim3(512), 0, stream,
                       x0, W1, b1, W2, out);
}

// Round 2
// 100.070 us; speedup vs baseline: 1.3811x; 1.0297x over previous
//
#include <hip/hip_runtime.h>
#include <stdint.h>

// HamiltonianFlow: x [256, 8, 32, 2] (q,p); H = 0.5*sum(p^2) + MLP(q).
// dq/dt = p, dp/dt = -W u(z), z = W^T q + b1, u = (1-tanh^2(z)).*W2.
// z-space iteration with M = W^T W (R15-R23 verified).
//
// R26 = R25 (4-step exchange, 1 barrier / 4 steps) + pipe rebalance:
//  * __shfl_xor butterflies -> v_permlane16/32_swap_b32 (pure VALU; with
//    a=b=x the swapped pair is {x[l&~16], x[l|16]} under either direction
//    convention, so a+b == shfl-butterfly bitwise). Removes 96 ds_permute
//    per CU per exchange from the per-CU LDS pipe + their serial latency.
//  * comp-pair (c0,c1) scalar math -> v_pk_fma/add/mul_f32 (VOP3P, 2 f32
//    per lane-instr): stage-z prediction, Y-combos, state update,
//    S-partials. Halves that VALU issue.
//  * exp(2z): fold the doubling into the stage-z constants (chain computes
//    2*z directly); u = (1-hh^2)*w2 == 4*w2*(r - r^2) with r = rcp(e+1),
//    via fma(-r,r,r). Same algebra, same rounding class.
// R25 recap: A-tile rows 4q+r = step-q stage-(r+1) u-vectors; quad q
// predicts its step's state from prev-exchange butterfly sums SA,SB
// (lag-4, err ~1e-6 z, ~100x below f16 u-rounding), one barrier + one
// 16-MFMA block per 4 steps; exact 4-step advance via SA/SB/SWB sums.
// ubuf (2 x 16 rows x US) unions setup-only mscr; XOR col-swizzle
// (c ^= ((row>>2)&3)<<3) kills the 4-row ds_read_b128 aliasing.
// FULL unroll on every reg-array access (R4: dynamic index => scratch).
// Numerics: f16 storage (W, M, u, S), fp32 MFMA accum + fp32 z1/P state.

typedef _Float16 v8h __attribute__((ext_vector_type(8)));
typedef float v4f __attribute__((ext_vector_type(4)));
typedef float vf2 __attribute__((ext_vector_type(2)));

#define NSTEPS 100
#define NEX 25    // 4 RK4 steps per exchange
#define WS 264    // wldsT row stride (f16): row = one W-COLUMN, 16B-aligned
#define US 272    // ubuf row stride, f16 (544 B == 32 mod 128)

// D(+=C) in VGPRs, A (packed-vector frag) in VGPRs, B (M-frag) from AGPRs.
#define MFMA_AV(C, A, B) \
    asm("v_mfma_f32_16x16x32_f16 %0, %1, %2, %0" : "+v"(C) : "v"(A), "a"(B))

// Packed-f32 pair ops (VOP3P): d = a*b+c / a+b / a*b on both halves.
#define PK_FMA(d, a, b, c) \
    asm("v_pk_fma_f32 %0, %1, %2, %3" : "=v"(d) : "v"(a), "v"(b), "v"(c))
#define PK_ADD(d, a, b) \
    asm("v_pk_add_f32 %0, %1, %2" : "=v"(d) : "v"(a), "v"(b))
#define PK_MUL(d, a, b) \
    asm("v_pk_mul_f32 %0, %1, %2" : "=v"(d) : "v"(a), "v"(b))

// 4-group butterfly sum over lanes {l, l^16, l^32, l^48}, pure VALU.
// permlaneN_swap(a,b) with a=b=x yields {x[l&~N], x[l|N]} (symmetric under
// either swap-direction convention); sums are f32-commutative => bitwise
// identical to the shfl_xor(16)+shfl_xor(32) butterfly.
__device__ __forceinline__ float bfly4(float x) {
    float a = x, b = x;
    asm("v_permlane16_swap_b32 %0, %1" : "+v"(a), "+v"(b));
    float s = a + b;
    float c = s, d = s;
    asm("v_permlane32_swap_b32 %0, %1" : "+v"(c), "+v"(d));
    return c + d;
}

// u/(4*w2) eval on pre-doubled arg zz = 2*z:  r = rcp(e^zz + 1);
// u = 4*w2*(r - r^2)  ==  (1 - tanh^2(z)) * w2  exactly in algebra.
__device__ __forceinline__ float ueval2(float zz, float w4) {
    float e_ = __expf(zz);
    float r_ = __builtin_amdgcn_rcpf(e_ + 1.f);   // vs IEEE div: ~1e-7 rel
    return w4 * __builtin_fmaf(-r_, r_, r_);
}

__global__ __launch_bounds__(512, 2)
void ham_kernel(const float* __restrict__ x0, const float* __restrict__ W1,
                const float* __restrict__ b1, const float* __restrict__ W2,
                float* __restrict__ out)
{
    __shared__ __align__(16)  _Float16 wldsT[256 * WS];  // 135168 B: W^T (f16)
    __shared__ __align__(128) char     upool[20480];     // mscr UNION ubuf
    float*    mscr = (float*)upool;                      // setup only
    _Float16* ubuf = (_Float16*)upool;                   // 2 x 16 rows x US

    const int t = threadIdx.x;
    const int w = t >> 6;          // wave 0..7: owns tiles {2w, 2w+1}
    const int l = t & 63;
    const int quad = l >> 4;       // step-within-exchange owned by this lane
    const int s = l & 15;          // owned column / A-row
    const int c0 = 32 * w + s;          // comp, tile 2w
    const int c1 = 32 * w + 16 + s;     // comp, tile 2w+1
    const int blk = blockIdx.x;
    const int sel = (s & 3) * US;  // prologue/epilogue A-row select (rows 0-3)

    // ---- stage W^T -> LDS f16: wldsT[c][r] = W[r][c] ----
    {
        const int c = t & 255;
        const int rbase = (t >> 8) * 128;
        #pragma unroll 1
        for (int r0 = 0; r0 < 128; r0 += 8) {
            v8h h;
            #pragma unroll
            for (int j = 0; j < 8; ++j)
                h[j] = (_Float16)W1[(rbase + r0 + j) * 256 + c];
            *(v8h*)(wldsT + c * WS + rbase + r0) = h;   // b128, one-time
        }
    }
    __syncthreads();

    // ---- wF: own-column W^T frags (B-op), contiguous b128 from wldsT ----
    v8h wF0[8], wF1[8];
    #pragma unroll
    for (int kk = 0; kk < 8; ++kk) {
        wF0[kk] = *(const v8h*)(wldsT + c0 * WS + 32 * kk + 8 * quad);
        wF1[kk] = *(const v8h*)(wldsT + c1 * WS + 32 * kk + 8 * quad);
    }

    // ---- build M = W^T W column-block frags wM0/wM1 (B-op: M[k][c]) ----
    v8h wM0[8], wM1[8];
    float* scr0 = mscr + w * 640;
    float* scr1 = scr0 + 320;
    #pragma unroll
    for (int kb = 0; kb < 16; ++kb) {
        v8h aM[8];   // A[m=s][k=8quad+j] = wldsT[(16kb+s)*WS + 32kk+8quad+j]
        #pragma unroll
        for (int kk = 0; kk < 8; ++kk)
            aM[kk] = *(const v8h*)(wldsT + (16 * kb + s) * WS
                                          + 32 * kk + 8 * quad);
        v4f D0 = {0.f,0.f,0.f,0.f}, D1 = {0.f,0.f,0.f,0.f};
        #pragma unroll
        for (int kk = 0; kk < 8; ++kk) {
            D0 = __builtin_amdgcn_mfma_f32_16x16x32_f16(aM[kk], wF0[kk], D0, 0, 0, 0);
            D1 = __builtin_amdgcn_mfma_f32_16x16x32_f16(aM[kk], wF1[kk], D1, 0, 0, 0);
        }
        *(v4f*)(scr0 + s * 20 + 4 * quad) = D0;
        *(v4f*)(scr1 + s * 20 + 4 * quad) = D1;
        asm volatile("s_waitcnt lgkmcnt(0)" ::: "memory");  // in-wave x-lane
        if ((quad >> 1) == (kb & 1)) {
            #pragma unroll
            for (int j = 0; j < 8; ++j) {
                wM0[kb >> 1][j] = (_Float16)scr0[s * 20 + 8 * (quad & 1) + j];
                wM1[kb >> 1][j] = (_Float16)scr1[s * 20 + 8 * (quad & 1) + j];
            }
        }
        asm volatile("s_waitcnt lgkmcnt(0)" ::: "memory");
    }
    __syncthreads();   // mscr reads (all waves) done before ubuf reuse

    const float b1r0 = b1[c0], b1r1 = b1[c1];
    const float w2r0 = W2[c0], w2r1 = W2[c1];
    const float w40 = 4.f * w2r0, w41 = 4.f * w2r1;
    float2 qp0 = ((const float2*)(x0 + (size_t)blk * 512))[c0];
    float2 qp1 = ((const float2*)(x0 + (size_t)blk * 512))[c1];
    const float q0o0 = qp0.x, p0o0 = qp0.y;
    const float q0o1 = qp1.x, p0o1 = qp1.y;

    // ---- prologue: buf0 rows {q0, p0, 0, 0} -> z1 (C[0]), P (C[1]) ----
    if (quad == 0) {
        ubuf[c0] = (_Float16)q0o0;  ubuf[c1] = (_Float16)q0o1;
        ubuf[US + c0] = (_Float16)p0o0;  ubuf[US + c1] = (_Float16)p0o1;
        ubuf[2 * US + c0] = (_Float16)0.f;  ubuf[2 * US + c1] = (_Float16)0.f;
        ubuf[3 * US + c0] = (_Float16)0.f;  ubuf[3 * US + c1] = (_Float16)0.f;
    }
    __syncthreads();
    vf2 z1v, Pv;
    {
        const _Float16* ab = ubuf + sel + 8 * quad;
        v4f C0a = {0.f,0.f,0.f,0.f}, C0b = {0.f,0.f,0.f,0.f};
        v4f C1a = {0.f,0.f,0.f,0.f}, C1b = {0.f,0.f,0.f,0.f};
        #pragma unroll
        for (int kk = 0; kk < 8; kk += 2) {
            v8h a0 = *(const v8h*)(ab + 32 * kk);
            v8h a1 = *(const v8h*)(ab + 32 * (kk + 1));
            C0a = __builtin_amdgcn_mfma_f32_16x16x32_f16(a0, wF0[kk], C0a, 0, 0, 0);
            C1a = __builtin_amdgcn_mfma_f32_16x16x32_f16(a0, wF1[kk], C1a, 0, 0, 0);
            C0b = __builtin_amdgcn_mfma_f32_16x16x32_f16(a1, wF0[kk + 1], C0b, 0, 0, 0);
            C1b = __builtin_amdgcn_mfma_f32_16x16x32_f16(a1, wF1[kk + 1], C1b, 0, 0, 0);
        }
        v4f C0s = C0a + C0b, C1s = C1a + C1b;
        z1v.x = C0s[0] + b1r0;  Pv.x = C0s[1];
        z1v.y = C1s[0] + b1r1;  Pv.y = C1s[1];
    }
    __syncthreads();   // prologue reads done before iter-0 overwrites buf0

    const float dt = 0.01f, hdt = 0.005f, dt6 = 0.01f / 6.f;
    const float dtdt6 = dt * dt6, hdt2 = hdt * hdt, dthdt = dt * hdt;
    // per-quad (step j = quad) prediction coefs (R25-verified):
    //   P_j ~ P - (j/4)*dt6*SBp ; z_j ~ z + j*dt*P - (j(j-1)/2)/4*dtdt6*SBp
    //                                    - (j/4)*dtdt6*SAp
    const float qf  = (float)quad;
    const float cP  = qf * 0.25f * dt6;
    const float cz1 = qf * dt;
    const float cz2 = (qf * (qf - 1.f) * 0.5f) * 0.25f * dtdt6;
    const float cz3 = qf * 0.25f * dtdt6;
    const float wB  = 3.f - qf;          // SWB weight (3-j)

    // hoisted vf2 constants (stage-z chain carries 2*z => doubled coefs)
    const vf2 KcPn    = {-cP, -cP};
    const vf2 K2cz1   = {2.f * cz1, 2.f * cz1};
    const vf2 K2cz2n  = {-2.f * cz2, -2.f * cz2};
    const vf2 K2cz3n  = {-2.f * cz3, -2.f * cz3};
    const vf2 K2hdt   = {2.f * hdt, 2.f * hdt};
    const vf2 K2hdt2n = {-2.f * hdt2, -2.f * hdt2};
    const vf2 K2dt    = {2.f * dt, 2.f * dt};
    const vf2 K2dthdtn= {-2.f * dthdt, -2.f * dthdt};
    const vf2 KwBv    = {wB, wB};
    const vf2 Kfourdt = {4.f * dt, 4.f * dt};
    const vf2 Kdtdt6n = {-dtdt6, -dtdt6};
    const vf2 Kdt6n   = {-dt6, -dt6};
    const vf2 K2v     = {2.f, 2.f};
    const vf2 Km4     = {-4.f, -4.f};

    // ubuf addressing: write rows 4q+i at swizzled col c ^ (q<<3);
    // read row s at k-chunk 8*(quad ^ ((s>>2)&3))  [XOR involution]
    const int c0w = c0 ^ (quad << 3);
    const int c1w = c1 ^ (quad << 3);
    _Float16* wbase0 = ubuf + 4 * quad * US + c0w;
    _Float16* wbase1 = ubuf + 4 * quad * US + c1w;
    const int sx = (s >> 2) & 3;
    const _Float16* rb = ubuf + s * US + 8 * (quad ^ sx);

    // prev-exchange lag state (exchange 0: zeros -> benign one-time
    // transient, err ~1e-5 stage-z, R25-verified class)
    vf2 SAp = {0.f, 0.f}, SBp = {0.f, 0.f};
    vf2 Y1L = {0.f, 0.f}, Y2L = {0.f, 0.f};
    vf2 S1p = {0.f, 0.f}, S23p = {0.f, 0.f};
    vf2 cn2 = {99.f - qf, 99.f - qf};

    #pragma unroll 1
    for (int e = 0; e < NEX; ++e) {
        const int bo = (e & 1) * (16 * US);   // double-buffer offset

        // ---- predicted state for own step; 4 stage 2z's; 8 u evals ----
        vf2 z1d; PK_ADD(z1d, z1v, z1v);
        vf2 Pp;  PK_FMA(Pp,  KcPn,    SBp, Pv);
        vf2 zp2; PK_FMA(zp2, K2cz1,   Pv,  z1d);
        PK_FMA(zp2, K2cz2n, SBp, zp2);
        PK_FMA(zp2, K2cz3n, SAp, zp2);
        vf2 zb2; PK_FMA(zb2, K2hdt,   Pp,  zp2);
        vf2 zc2; PK_FMA(zc2, K2hdt2n, Y1L, zb2);
        vf2 zd2; PK_FMA(zd2, K2dt,    Pp,  zp2);
        PK_FMA(zd2, K2dthdtn, Y2L, zd2);

        float ua0 = ueval2(zp2.x, w40), ua1 = ueval2(zp2.y, w41);
        float ub0 = ueval2(zb2.x, w40), ub1 = ueval2(zb2.y, w41);
        float uc0 = ueval2(zc2.x, w40), uc1 = ueval2(zc2.y, w41);
        float ud0 = ueval2(zd2.x, w40), ud1 = ueval2(zd2.y, w41);

        _Float16* wp0 = wbase0 + bo;
        _Float16* wp1 = wbase1 + bo;
        wp0[0]      = (_Float16)ua0;  wp1[0]      = (_Float16)ua1;
        wp0[US]     = (_Float16)ub0;  wp1[US]     = (_Float16)ub1;
        wp0[2 * US] = (_Float16)uc0;  wp1[2 * US] = (_Float16)uc1;
        wp0[3 * US] = (_Float16)ud0;  wp1[3 * US] = (_Float16)ud1;
        __syncthreads();   // the ONLY barrier per exchange (4 steps)

        // ---- ONE MFMA block: step-q Y1..Y4 for both comps, in-lane ----
        v4f C0s, C1s;
        {
            const _Float16* ab = rb + bo;
            v4f C0a = {0.f,0.f,0.f,0.f}, C0b = {0.f,0.f,0.f,0.f};
            v4f C1a = {0.f,0.f,0.f,0.f}, C1b = {0.f,0.f,0.f,0.f};
            #pragma unroll
            for (int kk = 0; kk < 8; kk += 2) {
                v8h a0 = *(const v8h*)(ab + 32 * kk);
                v8h a1 = *(const v8h*)(ab + 32 * (kk + 1));
                MFMA_AV(C0a, a0, wM0[kk]);
                MFMA_AV(C1a, a0, wM1[kk]);
                MFMA_AV(C0b, a1, wM0[kk + 1]);
                MFMA_AV(C1b, a1, wM1[kk + 1]);
            }
            C0s = C0a + C0b;  C1s = C1a + C1b;
        }
        // no second barrier: next exchange writes the OTHER buffer (R24).

        // ---- exact 4-step advance via quad-weighted butterfly sums ----
        vf2 Y1 = {C0s[0], C1s[0]};
        vf2 Y2 = {C0s[1], C1s[1]};
        vf2 Y3 = {C0s[2], C1s[2]};
        vf2 Y4 = {C0s[3], C1s[3]};
        vf2 tA;  PK_ADD(tA, Y2, Y3);
        vf2 Av;  PK_ADD(Av, Y1, tA);              // Y1+Y2+Y3
        vf2 Bv;  PK_ADD(Bv, Av, tA);  PK_ADD(Bv, Bv, Y4);  // Y1+2Y2+2Y3+Y4
        vf2 WBv; PK_MUL(WBv, KwBv, Bv);

        vf2 SA, SB, SWB;
        SA.x  = bfly4(Av.x);   SA.y  = bfly4(Av.y);
        SB.x  = bfly4(Bv.x);   SB.y  = bfly4(Bv.y);
        SWB.x = bfly4(WBv.x);  SWB.y = bfly4(WBv.y);

        PK_FMA(z1v, Kfourdt, Pv, z1v);            // + 4dt*P (old P)
        vf2 tS; PK_ADD(tS, SWB, SA);
        PK_FMA(z1v, Kdtdt6n, tS, z1v);            // - dt*dt6*SWB - dtdt6*SA
        PK_FMA(Pv, Kdt6n, SB, Pv);                // - dt6*SB

        SAp = SA;  SBp = SB;  Y1L = Y1;  Y2L = Y2;   // lag state

        // ---- per-lane S partials: full sp,sq for own step ----
        vf2 uAv = {ua0, ua1}, uBv = {ub0, ub1};
        vf2 uCv = {uc0, uc1}, uDv = {ud0, ud1};
        vf2 tv; PK_ADD(tv, uBv, uCv);
        vf2 sp; PK_ADD(sp, uAv, uDv);  PK_FMA(sp, K2v, tv, sp);
        vf2 sq; PK_ADD(sq, uAv, tv);
        PK_ADD(S1p, S1p, sp);
        PK_FMA(S23p, cn2, sp, S23p);  PK_ADD(S23p, S23p, sq);
        PK_ADD(cn2, cn2, Km4);
    }

    // ---- epilogue: reduce S over the 4 quads; buf0 rows {S1, S23, 0, 0} ----
    const float S1f0  = bfly4(S1p.x),  S1f1  = bfly4(S1p.y);
    const float S23f0 = bfly4(S23p.x), S23f1 = bfly4(S23p.y);
    __syncthreads();   // last exchange's reads (buf0, e=24) done
    if (quad == 0) {
        ubuf[c0] = (_Float16)S1f0;       ubuf[c1] = (_Float16)S1f1;
        ubuf[US + c0] = (_Float16)S23f0; ubuf[US + c1] = (_Float16)S23f1;
        ubuf[2 * US + c0] = (_Float16)0.f;  ubuf[2 * US + c1] = (_Float16)0.f;
        ubuf[3 * US + c0] = (_Float16)0.f;  ubuf[3 * US + c1] = (_Float16)0.f;
    }
    __syncthreads();
    // wBt[kk][j] = W[c][32kk+8quad+j] = wldsT[(32kk+8quad+j)*WS + c]
    v8h wBt0[8], wBt1[8];
    #pragma unroll
    for (int kk = 0; kk < 8; ++kk)
        #pragma unroll
        for (int j = 0; j < 8; ++j) {
            wBt0[kk][j] = wldsT[(32 * kk + 8 * quad + j) * WS + c0];
            wBt1[kk][j] = wldsT[(32 * kk + 8 * quad + j) * WS + c1];
        }
    float D10, D20, D11, D21;
    {
        const _Float16* ab = ubuf + sel + 8 * quad;
        v4f C0a = {0.f,0.f,0.f,0.f}, C0b = {0.f,0.f,0.f,0.f};
        v4f C1a = {0.f,0.f,0.f,0.f}, C1b = {0.f,0.f,0.f,0.f};
        #pragma unroll
        for (int kk = 0; kk < 8; kk += 2) {
            v8h a0 = *(const v8h*)(ab + 32 * kk);
            v8h a1 = *(const v8h*)(ab + 32 * (kk + 1));
            C0a = __builtin_amdgcn_mfma_f32_16x16x32_f16(a0, wBt0[kk], C0a, 0, 0, 0);
            C1a = __builtin_amdgcn_mfma_f32_16x16x32_f16(a0, wBt1[kk], C1a, 0, 0, 0);
            C0b = __builtin_amdgcn_mfma_f32_16x16x32_f16(a1, wBt0[kk + 1], C0b, 0, 0, 0);
            C1b = __builtin_amdgcn_mfma_f32_16x16x32_f16(a1, wBt1[kk + 1], C1b, 0, 0, 0);
        }
        v4f C0s = C0a + C0b, C1s = C1a + C1b;
        D10 = C0s[0];  D20 = C0s[1];
        D11 = C1s[0];  D21 = C1s[1];
    }
    const float dt6e = 0.01f / 6.f, dtdt6e = 0.01f * dt6e;
    float pT0 = p0o0 - dt6e * D10;
    float qT0 = q0o0 + 0.01f * (float)NSTEPS * p0o0 - dtdt6e * D20;
    float pT1 = p0o1 - dt6e * D11;
    float qT1 = q0o1 + 0.01f * (float)NSTEPS * p0o1 - dtdt6e * D21;

    if (quad == 0) {
        ((float2*)(out + (size_t)blk * 512))[c0] = make_float2(qT0, pT0);
        ((float2*)(out + (size_t)blk * 512))[c1] = make_float2(qT1, pT1);
    }
}

extern "C" void kernel_launch(void* const* d_in, const int* in_sizes, int n_in,
                              void* d_out, int out_size, void* d_ws, size_t ws_size,
                              hipStream_t stream) {
    const float* x0 = (const float*)d_in[0];
    const float* W1 = (const float*)d_in[1];
    const float* b1 = (const float*)d_in[2];
    const float* W2 = (const float*)d_in[3];
    // d_in[4] = b2: constant offset, no effect on the gradient/dynamics.
    float* out = (float*)d_out;
    hipLaunchKernelGGL(ham_kernel, dim3(256), dim3(512), 0, stream,
                       x0, W1, b1, W2, out);
}

// Round 3
// 97.783 us; speedup vs baseline: 1.4134x; 1.0234x over previous
//
#include <hip/hip_runtime.h>
#include <stdint.h>

// HamiltonianFlow: x [256, 8, 32, 2] (q,p); H = 0.5*sum(p^2) + MLP(q).
// dq/dt = p, dp/dt = -W u(z), z = W^T q + b1, u = (1-tanh^2(z)).*W2.
// z-space iteration with M = W^T W (R15-R23 verified).
//
// R27 = R26 (4-step exchange, permlane bfly, rcp/exp folds) restructured to
// 16 WAVES x 1 TILE (1024 threads): same per-CU totals (MFMA, u-evals,
// ds-writes; A-tile ds_reads double to 16x8KB/exchange ~ still sub-floor),
// but 4 waves/SIMD instead of 2 -> the exp/cvt chains, ds_read latency and
// MFMA chains latency-hide across waves. R26's counters showed the wall was
// stall, not throughput (VALUBusy 37 / Mfma 17 / LDS ~12 vs 4630cyc/exch).
// Single comp per lane -> scalar f32 math (drops all vf2 packing movs).
// Predictor now in {SB, SV=SWB+SA} via SWB ~ 1.5*SB proxy (same class as
// the R25-verified B_j ~ SB/4 proxy): 2 butterflies/exchange instead of 3;
// the 4-step state update stays EXACT:
//   z += 4dt*P - dtdt6*SV;  P -= dt6*SB
//   pred (step j=quad): Pp = P - (j/4)dt6*SBp;
//   zp2(=2z_j) = 2z + 2j*dt*P + [j(4-j)dtdt6/4]*SBp - [j*dtdt6/2]*SVp
// Stage args carry 2*z (exp-fold); u = 4*w2*(r-r^2), r=rcp(e^{2z}+1).
// ubuf: rows 4*step+stage hold u-vectors; XOR col-swizzle
// (c ^= ((row>>2)&3)<<3) kills 4-row ds_read_b128 aliasing; ONE barrier
// per exchange (R24 double-buffer race argument, unchanged with 16 waves).
// mscr 16x320 f32 = 20480 B (UNION ubuf, barrier between uses).
// FULL unroll on every reg-array access (R4: dynamic index => scratch).
// Numerics: f16 storage (W, M, u, S), fp32 MFMA accum + fp32 z/P state.

typedef _Float16 v8h __attribute__((ext_vector_type(8)));
typedef float v4f __attribute__((ext_vector_type(4)));

#define NSTEPS 100
#define NEX 25    // 4 RK4 steps per exchange
#define WS 264    // wldsT row stride (f16): row = one W-COLUMN, 16B-aligned
#define US 272    // ubuf row stride, f16 (544 B == 32 mod 128)

// D(+=C) in VGPRs, A (packed-vector frag) in VGPRs, B (M-frag) from AGPRs.
#define MFMA_AV(C, A, B) \
    asm("v_mfma_f32_16x16x32_f16 %0, %1, %2, %0" : "+v"(C) : "v"(A), "a"(B))

// 4-group butterfly sum over lanes {l, l^16, l^32, l^48}, pure VALU.
// permlaneN_swap(a,b) with a=b=x yields {x[l&~N], x[l|N]} under either
// direction convention; sums are commutative => == shfl_xor butterfly.
__device__ __forceinline__ float bfly4(float x) {
    float a = x, b = x;
    asm("v_permlane16_swap_b32 %0, %1" : "+v"(a), "+v"(b));
    float s = a + b;
    float c = s, d = s;
    asm("v_permlane32_swap_b32 %0, %1" : "+v"(c), "+v"(d));
    return c + d;
}

// u/(4*w2) eval on pre-doubled arg zz = 2*z:  r = rcp(e^zz + 1);
// u = 4*w2*(r - r^2)  ==  (1 - tanh^2(z)) * w2  exactly in algebra.
__device__ __forceinline__ float ueval2(float zz, float w4) {
    float e_ = __expf(zz);
    float r_ = __builtin_amdgcn_rcpf(e_ + 1.f);   // vs IEEE div: ~1e-7 rel
    return w4 * __builtin_fmaf(-r_, r_, r_);
}

__global__ __launch_bounds__(1024, 4)
void ham_kernel(const float* __restrict__ x0, const float* __restrict__ W1,
                const float* __restrict__ b1, const float* __restrict__ W2,
                float* __restrict__ out)
{
    __shared__ __align__(16)  _Float16 wldsT[256 * WS];  // 135168 B: W^T (f16)
    __shared__ __align__(128) char     upool[20480];     // mscr UNION ubuf
    float*    mscr = (float*)upool;                      // setup only
    _Float16* ubuf = (_Float16*)upool;                   // 2 x 16 rows x US

    const int t = threadIdx.x;
    const int w = t >> 6;          // wave 0..15: owns tile w (16 comps)
    const int l = t & 63;
    const int quad = l >> 4;       // step-within-exchange owned by this lane
    const int s = l & 15;          // owned column / A-row
    const int c0 = 16 * w + s;     // owned component
    const int blk = blockIdx.x;
    const int sel = (s & 3) * US;  // prologue/epilogue A-row select (rows 0-3)

    // ---- stage W^T -> LDS f16: wldsT[c][r] = W[r][c] ----
    {
        const int c = t & 255;
        const int rbase = (t >> 8) * 64;   // 4 quarters x 64 rows
        #pragma unroll 1
        for (int r0 = 0; r0 < 64; r0 += 8) {
            v8h h;
            #pragma unroll
            for (int j = 0; j < 8; ++j)
                h[j] = (_Float16)W1[(rbase + r0 + j) * 256 + c];
            *(v8h*)(wldsT + c * WS + rbase + r0) = h;   // b128, one-time
        }
    }
    __syncthreads();

    // ---- wF: own-column W^T frag (B-op), contiguous b128 from wldsT ----
    v8h wF0[8];
    #pragma unroll
    for (int kk = 0; kk < 8; ++kk)
        wF0[kk] = *(const v8h*)(wldsT + c0 * WS + 32 * kk + 8 * quad);

    // ---- build M = W^T W column-block frags wM0 (B-op: M[k][c0]) ----
    v8h wM0[8];
    float* scr0 = mscr + w * 320;
    #pragma unroll
    for (int kb = 0; kb < 16; ++kb) {
        v8h aM[8];   // A[m=s][k=8quad+j] = wldsT[(16kb+s)*WS + 32kk+8quad+j]
        #pragma unroll
        for (int kk = 0; kk < 8; ++kk)
            aM[kk] = *(const v8h*)(wldsT + (16 * kb + s) * WS
                                          + 32 * kk + 8 * quad);
        v4f D0 = {0.f,0.f,0.f,0.f};
        #pragma unroll
        for (int kk = 0; kk < 8; ++kk)
            D0 = __builtin_amdgcn_mfma_f32_16x16x32_f16(aM[kk], wF0[kk], D0, 0, 0, 0);
        *(v4f*)(scr0 + s * 20 + 4 * quad) = D0;
        asm volatile("s_waitcnt lgkmcnt(0)" ::: "memory");  // in-wave x-lane
        if ((quad >> 1) == (kb & 1)) {
            #pragma unroll
            for (int j = 0; j < 8; ++j)
                wM0[kb >> 1][j] = (_Float16)scr0[s * 20 + 8 * (quad & 1) + j];
        }
        asm volatile("s_waitcnt lgkmcnt(0)" ::: "memory");
    }
    __syncthreads();   // mscr reads (all waves) done before ubuf reuse

    const float b1r0 = b1[c0];
    const float w4 = 4.f * W2[c0];
    float2 qp0 = ((const float2*)(x0 + (size_t)blk * 512))[c0];
    const float q0o0 = qp0.x, p0o0 = qp0.y;

    // ---- prologue: buf0 rows {q0, p0, 0, 0} -> z1 (C[0]), P (C[1]) ----
    if (quad == 0) {
        ubuf[c0] = (_Float16)q0o0;
        ubuf[US + c0] = (_Float16)p0o0;
        ubuf[2 * US + c0] = (_Float16)0.f;
        ubuf[3 * US + c0] = (_Float16)0.f;
    }
    __syncthreads();
    float z1, P;
    {
        const _Float16* ab = ubuf + sel + 8 * quad;
        v4f C0a = {0.f,0.f,0.f,0.f}, C0b = {0.f,0.f,0.f,0.f};
        #pragma unroll
        for (int kk = 0; kk < 8; kk += 2) {
            v8h a0 = *(const v8h*)(ab + 32 * kk);
            v8h a1 = *(const v8h*)(ab + 32 * (kk + 1));
            C0a = __builtin_amdgcn_mfma_f32_16x16x32_f16(a0, wF0[kk], C0a, 0, 0, 0);
            C0b = __builtin_amdgcn_mfma_f32_16x16x32_f16(a1, wF0[kk + 1], C0b, 0, 0, 0);
        }
        v4f C0s = C0a + C0b;
        z1 = C0s[0] + b1r0;  P = C0s[1];
    }
    __syncthreads();   // prologue reads done before iter-0 overwrites buf0

    const float dt = 0.01f, hdt = 0.005f, dt6 = 0.01f / 6.f;
    const float dtdt6 = dt * dt6, hdt2 = hdt * hdt, dthdt = dt * hdt;
    const float fourdt = 4.f * dt;
    // per-quad (step j = quad) prediction coefs in {SBp, SVp} form:
    //   Pp = P - (j/4)dt6*SBp
    //   zp2 = 2z + 2j*dt*P + [j(4-j)dtdt6/4]*SBp - [j*dtdt6/2]*SVp
    // (from SAp = SVp - 1.5*SBp folded into the R25-verified coefs)
    const float qf  = (float)quad;
    const float cPn   = -(qf * 0.25f * dt6);
    const float K2cz1 = 2.f * qf * dt;
    const float K2B   = qf * (4.f - qf) * dtdt6 * 0.25f;
    const float K2Vn  = -(qf * dtdt6 * 0.5f);
    const float K2hdt = 2.f * hdt;
    const float K2hdt2n = -2.f * hdt2;
    const float K2dt  = 2.f * dt;
    const float K2dthdtn = -2.f * dthdt;
    const float wB  = 3.f - qf;          // SWB weight (3-j)

    // ubuf addressing: write rows 4q+i at swizzled col c ^ (q<<3);
    // read row s at k-chunk 8*(quad ^ ((s>>2)&3))  [XOR involution]
    const int c0w = c0 ^ (quad << 3);
    _Float16* wbase0 = ubuf + 4 * quad * US + c0w;
    const int sx = (s >> 2) & 3;
    const _Float16* rb = ubuf + s * US + 8 * (quad ^ sx);

    // prev-exchange lag state (exchange 0: zeros -> benign one-time
    // transient, err ~1e-5 stage-z, R25-verified class)
    float SBp = 0.f, SVp = 0.f;
    float Y1L = 0.f, Y2L = 0.f;
    float S1p = 0.f, S23p = 0.f;
    float cn = 99.f - qf;

    #pragma unroll 1
    for (int e = 0; e < NEX; ++e) {
        const int bo = (e & 1) * (16 * US);   // double-buffer offset

        // ---- predicted state for own step; 4 stage 2z's; 4 u evals ----
        float Pp  = __builtin_fmaf(cPn, SBp, P);
        float zp2 = __builtin_fmaf(K2cz1, P, z1 + z1);
        zp2 = __builtin_fmaf(K2B, SBp, zp2);
        zp2 = __builtin_fmaf(K2Vn, SVp, zp2);
        float zb2 = __builtin_fmaf(K2hdt, Pp, zp2);
        float zc2 = __builtin_fmaf(K2hdt2n, Y1L, zb2);
        float zd2 = __builtin_fmaf(K2dt, Pp, zp2);
        zd2 = __builtin_fmaf(K2dthdtn, Y2L, zd2);

        float ua = ueval2(zp2, w4);
        float ub = ueval2(zb2, w4);
        float uc = ueval2(zc2, w4);
        float ud = ueval2(zd2, w4);

        _Float16* wp0 = wbase0 + bo;
        wp0[0]      = (_Float16)ua;
        wp0[US]     = (_Float16)ub;
        wp0[2 * US] = (_Float16)uc;
        wp0[3 * US] = (_Float16)ud;
        __syncthreads();   // the ONLY barrier per exchange (4 steps)

        // ---- ONE MFMA block: step-q Y1..Y4 for own comp, in-lane ----
        v4f C0s;
        {
            const _Float16* ab = rb + bo;
            v4f C0a = {0.f,0.f,0.f,0.f}, C0b = {0.f,0.f,0.f,0.f};
            #pragma unroll
            for (int kk = 0; kk < 8; kk += 2) {
                v8h a0 = *(const v8h*)(ab + 32 * kk);
                v8h a1 = *(const v8h*)(ab + 32 * (kk + 1));
                MFMA_AV(C0a, a0, wM0[kk]);
                MFMA_AV(C0b, a1, wM0[kk + 1]);
            }
            C0s = C0a + C0b;
        }
        // no second barrier: next exchange writes the OTHER buffer (R24).

        // ---- exact 4-step advance via quad-weighted butterfly sums ----
        float Y1 = C0s[0], Y2 = C0s[1], Y3 = C0s[2], Y4 = C0s[3];
        float tA = Y2 + Y3;
        float A  = Y1 + tA;                    // Y1+Y2+Y3
        float B  = A + tA + Y4;                // Y1+2Y2+2Y3+Y4
        float V  = __builtin_fmaf(wB, B, A);   // (3-j)*B + A
        float SB = bfly4(B);
        float SV = bfly4(V);                   // = SWB + SA (exact)

        z1 = __builtin_fmaf(fourdt, P, z1);    // z += 4dt*P (old P)
        z1 = __builtin_fmaf(-dtdt6, SV, z1);   //    - dt*dt6*SWB - dtdt6*SA
        P  = __builtin_fmaf(-dt6, SB, P);      // P -= dt6*SB

        SBp = SB;  SVp = SV;  Y1L = Y1;  Y2L = Y2;   // lag state

        // ---- per-lane S partials: full sp,sq for own step ----
        float tv = ub + uc;
        float sp = __builtin_fmaf(2.f, tv, ua + ud);
        float sq = ua + tv;
        S1p += sp;
        S23p = __builtin_fmaf(cn, sp, S23p) + sq;
        cn -= 4.f;
    }

    // ---- epilogue: reduce S over the 4 quads; buf0 rows {S1, S23, 0, 0} ----
    const float S1f  = bfly4(S1p);
    const float S23f = bfly4(S23p);
    __syncthreads();   // last exchange's reads (buf0, e=24) done
    if (quad == 0) {
        ubuf[c0] = (_Float16)S1f;
        ubuf[US + c0] = (_Float16)S23f;
        ubuf[2 * US + c0] = (_Float16)0.f;
        ubuf[3 * US + c0] = (_Float16)0.f;
    }
    __syncthreads();
    // wBt[kk][j] = W[c0][32kk+8quad+j] = wldsT[(32kk+8quad+j)*WS + c0]
    v8h wBt0[8];
    #pragma unroll
    for (int kk = 0; kk < 8; ++kk)
        #pragma unroll
        for (int j = 0; j < 8; ++j)
            wBt0[kk][j] = wldsT[(32 * kk + 8 * quad + j) * WS + c0];
    float D10, D20;
    {
        const _Float16* ab = ubuf + sel + 8 * quad;
        v4f C0a = {0.f,0.f,0.f,0.f}, C0b = {0.f,0.f,0.f,0.f};
        #pragma unroll
        for (int kk = 0; kk < 8; kk += 2) {
            v8h a0 = *(const v8h*)(ab + 32 * kk);
            v8h a1 = *(const v8h*)(ab + 32 * (kk + 1));
            C0a = __builtin_amdgcn_mfma_f32_16x16x32_f16(a0, wBt0[kk], C0a, 0, 0, 0);
            C0b = __builtin_amdgcn_mfma_f32_16x16x32_f16(a1, wBt0[kk + 1], C0b, 0, 0, 0);
        }
        v4f C0s = C0a + C0b;
        D10 = C0s[0];  D20 = C0s[1];
    }
    const float dt6e = 0.01f / 6.f, dtdt6e = 0.01f * dt6e;
    float pT0 = p0o0 - dt6e * D10;
    float qT0 = q0o0 + 0.01f * (float)NSTEPS * p0o0 - dtdt6e * D20;

    if (quad == 0)
        ((float2*)(out + (size_t)blk * 512))[c0] = make_float2(qT0, pT0);
}

extern "C" void kernel_launch(void* const* d_in, const int* in_sizes, int n_in,
                              void* d_out, int out_size, void* d_ws, size_t ws_size,
                              hipStream_t stream) {
    const float* x0 = (const float*)d_in[0];
    const float* W1 = (const float*)d_in[1];
    const float* b1 = (const float*)d_in[2];
    const float* W2 = (const float*)d_in[3];
    // d_in[4] = b2: constant offset, no effect on the gradient/dynamics.
    float* out = (float*)d_out;
    hipLaunchKernelGGL(ham_kernel, dim3(256), dim3(1024), 0, stream,
                       x0, W1, b1, W2, out);
}